// Round 4
// baseline (197.822 us; speedup 1.0000x reference)
//
#include <hip/hip_runtime.h>
#include <hip/hip_bf16.h>
#include <hip/hip_fp16.h>

// out[e] = relu(z_s[row[e]]@W1_top + z_c[col[e]]@W1_bot + b1) @ W2 + b2
// u_s = z_s@W1_top + b1, u_c = z_c@W1_bot (both f16 in ws); per edge:
// out = sum_k relu(u_s[row][k]+u_c[col][k]) * W2[k] + b2.
//
// R4: edge phase is L2-traffic bound. Bucket edges by row range (64 buckets);
// XCD x owns contiguous buckets [8x,8x+8) and sweeps them SERIALLY so the live
// us window is ~400KB and uc (~5.1MB) gets most of the 4MB L2. Edge id rides
// along in eB -> direct scattered out[e] store, no pos/unscatter pass.

typedef _Float16 half2v __attribute__((ext_vector_type(2)));
typedef _Float16 half8v __attribute__((ext_vector_type(8)));
typedef __fp16   fp16x2 __attribute__((ext_vector_type(2)));
typedef float    float4v __attribute__((ext_vector_type(4)));

#define NB  64
#define CAP 17408   // avg 15625, sigma ~124 -> +14 sigma; inline fallback anyway

// ---- Kernel 1: W1 [256,128] fp32 -> Wt[half][n][k] f16 (LDS transpose), W2 -> f16 ----
__global__ __launch_bounds__(256) void conv_w(const float* __restrict__ W1,
                                              const float* __restrict__ W2,
                                              _Float16* __restrict__ Wt,
                                              _Float16* __restrict__ w2h,
                                              int* __restrict__ cnt) {
    int b = blockIdx.x, t = threadIdx.x;
    if (b == 8) {
        if (t < 128) w2h[t] = (_Float16)W2[t];
        if (t < NB)  cnt[t] = 0;              // zero bucket counters each replay
        return;
    }
    __shared__ _Float16 lds[32][136];
    int h = b >> 2, n0 = (b & 3) * 32;
    for (int i = 0; i < 16; ++i) {
        int idx = i * 256 + t;            // 4096 = 128k x 32n
        int k = idx >> 5, nn = idx & 31;
        lds[nn][k] = (_Float16)W1[(h * 128 + k) * 128 + n0 + nn];
    }
    __syncthreads();
    for (int j = 0; j < 2; ++j) {
        int idx = j * 256 + t;            // 512 = 32n x 16 chunks
        int nn = idx >> 4, kc = idx & 15;
        half8v v;
        #pragma unroll
        for (int q = 0; q < 8; ++q) v[q] = lds[nn][kc * 8 + q];
        *(half8v*)&Wt[((h * 128 + n0 + nn) * 128) + kc * 8] = v;
    }
}

// ---- Kernel 2: fused U_s / U_c GEMM, MFMA 16x16x32 f16, vectorized epilogue ----
__global__ __launch_bounds__(256) void gemm_u(
    const float* __restrict__ Zs, const float* __restrict__ Zc,
    const _Float16* __restrict__ Wt, const float* __restrict__ b1,
    _Float16* __restrict__ Us, _Float16* __restrict__ Uc,
    int Ms, int Mc, int nbs)
{
    __shared__ uint4 ldsW[2048];          // 128 x 16 chunks, swizzled, 32 KiB
    const int bid = blockIdx.x, t = threadIdx.x;

    const float* Z; _Float16* U; const _Float16* W; int M, m0, addB;
    if (bid < nbs) { Z = Zs; U = Us; M = Ms; m0 = bid * 64;         W = Wt;         addB = 1; }
    else           { Z = Zc; U = Uc; M = Mc; m0 = (bid - nbs) * 64; W = Wt + 16384; addB = 0; }

    const uint4* Wv = (const uint4*)W;    // [n][16 chunks]
    #pragma unroll
    for (int i = 0; i < 8; ++i) {
        int j = i * 256 + t;              // 2048
        int n = j >> 4, ch = j & 15;
        ldsW[n * 16 + (ch ^ ((n >> 3) & 7))] = Wv[j];
    }
    __syncthreads();

    const int wave = t >> 6, lane = t & 63, quad = lane >> 4, l16 = lane & 15;
    int mrow = m0 + wave * 16 + l16;
    int mload = mrow < M ? mrow : M - 1;  // clamp; stores guarded
    const float* zrow = Z + (long)mload * 128;

    float4v acc[8];
    #pragma unroll
    for (int nt = 0; nt < 8; ++nt) acc[nt] = (float4v)(0.0f);

    #pragma unroll
    for (int c = 0; c < 4; ++c) {
        const float4v* pa = (const float4v*)(zrow + c * 32 + quad * 8);
        float4v a0 = pa[0], a1 = pa[1];
        fp16x2 p[4];
        p[0] = __builtin_amdgcn_cvt_pkrtz(a0[0], a0[1]);
        p[1] = __builtin_amdgcn_cvt_pkrtz(a0[2], a0[3]);
        p[2] = __builtin_amdgcn_cvt_pkrtz(a1[0], a1[1]);
        p[3] = __builtin_amdgcn_cvt_pkrtz(a1[2], a1[3]);
        half8v af;
        __builtin_memcpy(&af, &p[0], 16);
        const int ch = c * 4 + quad;
        #pragma unroll
        for (int nt = 0; nt < 8; ++nt) {
            const int n = l16 * 8 + nt;
            const half8v* pb = (const half8v*)&ldsW[n * 16 + (ch ^ (l16 & 7))];
            acc[nt] = __builtin_amdgcn_mfma_f32_16x16x32_f16(af, *pb, acc[nt], 0, 0, 0);
        }
    }

    float bv[8];
    if (addB) {
        const float4v* pb1 = (const float4v*)(b1 + l16 * 8);
        float4v x0 = pb1[0], x1 = pb1[1];
        bv[0]=x0[0]; bv[1]=x0[1]; bv[2]=x0[2]; bv[3]=x0[3];
        bv[4]=x1[0]; bv[5]=x1[1]; bv[6]=x1[2]; bv[7]=x1[3];
    } else {
        #pragma unroll
        for (int i = 0; i < 8; ++i) bv[i] = 0.0f;
    }

    const int rbase = m0 + wave * 16 + quad * 4;
    #pragma unroll
    for (int r = 0; r < 4; ++r) {
        int rr = rbase + r;
        if (rr < M) {
            half8v o;
            #pragma unroll
            for (int nt = 0; nt < 8; ++nt) o[nt] = (_Float16)(acc[nt][r] + bv[nt]);
            *(half8v*)&U[(long)rr * 128 + l16 * 8] = o;
        }
    }
}

// ---- Kernel B1: bucket edges by row range into (rB, cB, eB) segments.
// Block-local LDS histogram -> <=64 global atomics/block. Overflow (never,
// statistically) computes the edge inline. ----
__global__ __launch_bounds__(256) void bucket_scatter(
    const int* __restrict__ row, const int* __restrict__ col,
    int* __restrict__ rB, int* __restrict__ cB, int* __restrict__ eB,
    int* __restrict__ cnt, int E, float scale,
    const _Float16* __restrict__ us, const _Float16* __restrict__ uc,
    const _Float16* __restrict__ w2h, const float* __restrict__ b2,
    float* __restrict__ out)
{
    __shared__ int hist[NB], base[NB], hist2[NB];
    const int t = threadIdx.x;
    if (t < NB) { hist[t] = 0; hist2[t] = 0; }
    __syncthreads();
    const long e0 = (long)blockIdx.x * 1024 + t;
    int r[4], c[4], bk[4];
    bool v[4];
    #pragma unroll
    for (int k = 0; k < 4; ++k) {
        long e = e0 + k * 256;
        v[k] = e < (long)E;
        long ee = v[k] ? e : 0;
        r[k] = __builtin_nontemporal_load(&row[ee]);
        c[k] = __builtin_nontemporal_load(&col[ee]);
        int b = (int)((float)r[k] * scale);
        bk[k] = b > NB - 1 ? NB - 1 : b;
        if (v[k]) atomicAdd(&hist[bk[k]], 1);
    }
    __syncthreads();
    if (t < NB) base[t] = atomicAdd(&cnt[t], hist[t]);
    __syncthreads();
    #pragma unroll
    for (int k = 0; k < 4; ++k) {
        if (!v[k]) continue;
        int o = atomicAdd(&hist2[bk[k]], 1);
        int slot = base[bk[k]] + o;
        long e = e0 + k * 256;
        if (slot < CAP) {
            int g = bk[k] * CAP + slot;
            rB[g] = r[k];
            cB[g] = c[k];
            eB[g] = (int)e;
        } else {
            // statistically-never overflow: compute inline
            float s = b2[0];
            for (int kk = 0; kk < 128; ++kk) {
                float h = (float)us[(long)r[k] * 128 + kk] + (float)uc[(long)c[k] * 128 + kk];
                s += fmaxf(h, 0.0f) * (float)w2h[kk];
            }
            out[e] = s;
        }
    }
}

// ---- Kernel B2: gather + relu-dot. XCD x (= bid%8, round-robin dispatch) owns
// the CONTIGUOUS bucket range [8x, 8x+8) (3.2MB contiguous us slice, fetched by
// exactly one XCD) and its 256 resident blocks sweep those buckets SERIALLY ->
// live us window ~400KB; uc gets the rest of the 4MB L2. Direct out[e] store. ----
__global__ __launch_bounds__(256) void edge_bucket(
    const int* __restrict__ rB, const int* __restrict__ cB,
    const int* __restrict__ eB, const int* __restrict__ cnt,
    const _Float16* __restrict__ us, const _Float16* __restrict__ uc,
    const _Float16* __restrict__ w2h, const float* __restrict__ b2,
    float* __restrict__ out)
{
    const int t = threadIdx.x, sub = t & 7;
    const int x = blockIdx.x & 7;               // XCD (blockIdx%8 heuristic)
    const int l = blockIdx.x >> 3;              // 0..255 local block on XCD

    const uint4* pw = (const uint4*)(w2h + sub * 16);
    uint4 w0 = pw[0], w1 = pw[1];
    half2v W[8];
    *(uint4*)&W[0] = w0; *(uint4*)&W[4] = w1;
    const float bb = b2[0];
    const half2v zero = {(_Float16)0, (_Float16)0};

    #pragma unroll 1
    for (int bl = 0; bl < NB / 8; ++bl) {       // serial bucket sweep
        const int b = x * (NB / 8) + bl;
        int n = cnt[b]; n = n < CAP ? n : CAP;
        const int seg = b * CAP;
        #pragma unroll 1
        for (int i0 = l * 32; i0 < n; i0 += 256 * 32) {
            int i = i0 + (t >> 3);
            bool act = i < n;
            int ii = act ? i : 0;
            int r = __builtin_nontemporal_load(&rB[seg + ii]);
            int c = __builtin_nontemporal_load(&cB[seg + ii]);
            const uint4* pa = (const uint4*)(us + (long)r * 128 + sub * 16);
            const uint4* pb = (const uint4*)(uc + (long)c * 128 + sub * 16);
            uint4 a0 = pa[0], a1 = pa[1];
            uint4 c0 = pb[0], c1 = pb[1];
            half2v A[8], B[8];
            *(uint4*)&A[0] = a0; *(uint4*)&A[4] = a1;
            *(uint4*)&B[0] = c0; *(uint4*)&B[4] = c1;
            float s = 0.0f;
            #pragma unroll
            for (int q = 0; q < 8; ++q) {
                half2v h = A[q] + B[q];                   // v_pk_add_f16
                h = __builtin_elementwise_max(h, zero);   // v_pk_max_f16
                s += (float)h[0] * (float)W[q][0];
                s += (float)h[1] * (float)W[q][1];
            }
            s += __shfl_xor(s, 1);
            s += __shfl_xor(s, 2);
            s += __shfl_xor(s, 4);
            if (sub == 0 && act) {
                int e = __builtin_nontemporal_load(&eB[seg + ii]);
                __builtin_nontemporal_store(s + bb, &out[e]);
            }
        }
    }
}

// ---- Fallback: original direct edge kernel (used if workspace too small) ----
__global__ __launch_bounds__(256) void edge_kernel(
    const int* __restrict__ row, const int* __restrict__ col,
    const _Float16* __restrict__ us, const _Float16* __restrict__ uc,
    const _Float16* __restrict__ w2h, const float* __restrict__ b2,
    float* __restrict__ out, int E)
{
    const int t = threadIdx.x;
    const int sub = t & 7;
    long e = (long)blockIdx.x * 32 + (t >> 3);
    if (e >= E) return;
    int r = row[e], c = col[e];

    const uint4* pa = (const uint4*)(us  + (long)r * 128 + sub * 16);
    const uint4* pb = (const uint4*)(uc  + (long)c * 128 + sub * 16);
    const uint4* pw = (const uint4*)(w2h + sub * 16);
    uint4 a0 = pa[0], a1 = pa[1];
    uint4 c0 = pb[0], c1 = pb[1];
    uint4 w0 = pw[0], w1 = pw[1];

    half2v A[8], B[8], W[8];
    *(uint4*)&A[0] = a0; *(uint4*)&A[4] = a1;
    *(uint4*)&B[0] = c0; *(uint4*)&B[4] = c1;
    *(uint4*)&W[0] = w0; *(uint4*)&W[4] = w1;

    const half2v zero = {(_Float16)0, (_Float16)0};
    float s = 0.0f;
    #pragma unroll
    for (int i = 0; i < 8; ++i) {
        half2v h = A[i] + B[i];
        h = __builtin_elementwise_max(h, zero);
        s += (float)h[0] * (float)W[i][0];
        s += (float)h[1] * (float)W[i][1];
    }
    s += __shfl_xor(s, 1);
    s += __shfl_xor(s, 2);
    s += __shfl_xor(s, 4);
    if (sub == 0) out[e] = s + b2[0];
}

extern "C" void kernel_launch(void* const* d_in, const int* in_sizes, int n_in,
                              void* d_out, int out_size, void* d_ws, size_t ws_size,
                              hipStream_t stream) {
    const float* zs  = (const float*)d_in[0];
    const float* zc  = (const float*)d_in[1];
    const int*   row = (const int*)d_in[2];
    const int*   col = (const int*)d_in[3];
    const float* W1  = (const float*)d_in[4];
    const float* b1  = (const float*)d_in[5];
    const float* W2  = (const float*)d_in[6];
    const float* b2  = (const float*)d_in[7];
    float* out = (float*)d_out;

    const int Ms = in_sizes[0] / 128;   // 100000
    const int Mc = in_sizes[1] / 128;   // 20000
    const int E  = in_sizes[2];         // 1000000

    // workspace layout (256B-aligned chunks)
    char* wsb = (char*)d_ws;
    _Float16* Wt  = (_Float16*)wsb;                      // 64 KiB
    _Float16* w2h = (_Float16*)(wsb + 65536);            // 256 B
    int*      cnt = (int*)(wsb + 65792);                 // 256 B (64 ints)
    size_t off = 66048;
    _Float16* us = (_Float16*)(wsb + off);  off += (size_t)Ms * 256;  // f16
    _Float16* uc = (_Float16*)(wsb + off);  off += (size_t)Mc * 256;
    int* rB = (int*)(wsb + off);  off += (size_t)NB * CAP * 4;
    int* cB = (int*)(wsb + off);  off += (size_t)NB * CAP * 4;
    int* eB = (int*)(wsb + off);  off += (size_t)NB * CAP * 4;
    const bool bucketed = (off <= ws_size);

    const int nbs = (Ms + 63) / 64, nbc = (Mc + 63) / 64;

    conv_w<<<9, 256, 0, stream>>>(W1, W2, Wt, w2h, cnt);
    gemm_u<<<nbs + nbc, 256, 0, stream>>>(zs, zc, Wt, b1, us, uc, Ms, Mc, nbs);
    if (bucketed) {
        bucket_scatter<<<(E + 1023) / 1024, 256, 0, stream>>>(
            row, col, rB, cB, eB, cnt, E, (float)NB / (float)Ms,
            us, uc, w2h, b2, out);
        edge_bucket<<<2048, 256, 0, stream>>>(rB, cB, eB, cnt, us, uc, w2h, b2, out);
    } else {
        edge_kernel<<<(E + 31) / 32, 256, 0, stream>>>(row, col, us, uc, w2h, b2, out, E);
    }
    (void)n_in; (void)out_size;
}

// Round 6
// 190.236 us; speedup vs baseline: 1.0399x; 1.0399x over previous
//
#include <hip/hip_runtime.h>
#include <hip/hip_bf16.h>
#include <hip/hip_fp16.h>

// out[e] = relu(z_s[row[e]]@W1_top + z_c[col[e]]@W1_bot + b1) @ W2 + b2
// u_s = z_s@W1_top + b1, u_c = z_c@W1_bot (both f16 in ws); per edge:
// out = sum_k relu(u_s[row][k]+u_c[col][k]) * W2[k] + b2.
//
// R5/R6: serial-sweep bucketing (validated: FETCH 136->82MB) with the two R4
// pathologies fixed: (1) coalesced outB + unscatter instead of scattered 4B NT
// out stores (R4: WRITE_SIZE 30MB, RMW-bound); (2) 8x-replicated global bucket
// counters (R4: 977-long device-atomic chains on 64 addrs ~= 30us scatter).
// R6 fix: (r,c) pair packed as long (HIP int2 is a class; nontemporal builtin
// rejects it).

typedef _Float16 half2v __attribute__((ext_vector_type(2)));
typedef _Float16 half8v __attribute__((ext_vector_type(8)));
typedef __fp16   fp16x2 __attribute__((ext_vector_type(2)));
typedef float    float4v __attribute__((ext_vector_type(4)));

#define NB   64     // row-range buckets; XCD x owns [8x, 8x+8)
#define NR   8      // counter replicas = subsegments per bucket (by bid%8)
#define CAPS 2176   // per-subsegment cap; mean 1953, sigma ~44 -> ~5 sigma

// ---- Kernel 1: W1 [256,128] fp32 -> Wt[half][n][k] f16 (LDS transpose), W2 -> f16 ----
__global__ __launch_bounds__(256) void conv_w(const float* __restrict__ W1,
                                              const float* __restrict__ W2,
                                              _Float16* __restrict__ Wt,
                                              _Float16* __restrict__ w2h,
                                              int* __restrict__ cnt) {
    int b = blockIdx.x, t = threadIdx.x;
    if (b == 8) {
        if (t < 128) w2h[t] = (_Float16)W2[t];
        for (int i = t; i < NB * NR; i += 256) cnt[i] = 0;   // re-zero each replay
        return;
    }
    __shared__ _Float16 lds[32][136];
    int h = b >> 2, n0 = (b & 3) * 32;
    for (int i = 0; i < 16; ++i) {
        int idx = i * 256 + t;            // 4096 = 128k x 32n
        int k = idx >> 5, nn = idx & 31;
        lds[nn][k] = (_Float16)W1[(h * 128 + k) * 128 + n0 + nn];
    }
    __syncthreads();
    for (int j = 0; j < 2; ++j) {
        int idx = j * 256 + t;            // 512 = 32n x 16 chunks
        int nn = idx >> 4, kc = idx & 15;
        half8v v;
        #pragma unroll
        for (int q = 0; q < 8; ++q) v[q] = lds[nn][kc * 8 + q];
        *(half8v*)&Wt[((h * 128 + n0 + nn) * 128) + kc * 8] = v;
    }
}

// ---- Kernel 2: fused U_s / U_c GEMM, MFMA 16x16x32 f16, vectorized epilogue ----
__global__ __launch_bounds__(256) void gemm_u(
    const float* __restrict__ Zs, const float* __restrict__ Zc,
    const _Float16* __restrict__ Wt, const float* __restrict__ b1,
    _Float16* __restrict__ Us, _Float16* __restrict__ Uc,
    int Ms, int Mc, int nbs)
{
    __shared__ uint4 ldsW[2048];          // 128 x 16 chunks, swizzled, 32 KiB
    const int bid = blockIdx.x, t = threadIdx.x;

    const float* Z; _Float16* U; const _Float16* W; int M, m0, addB;
    if (bid < nbs) { Z = Zs; U = Us; M = Ms; m0 = bid * 64;         W = Wt;         addB = 1; }
    else           { Z = Zc; U = Uc; M = Mc; m0 = (bid - nbs) * 64; W = Wt + 16384; addB = 0; }

    const uint4* Wv = (const uint4*)W;    // [n][16 chunks]
    #pragma unroll
    for (int i = 0; i < 8; ++i) {
        int j = i * 256 + t;              // 2048
        int n = j >> 4, ch = j & 15;
        ldsW[n * 16 + (ch ^ ((n >> 3) & 7))] = Wv[j];
    }
    __syncthreads();

    const int wave = t >> 6, lane = t & 63, quad = lane >> 4, l16 = lane & 15;
    int mrow = m0 + wave * 16 + l16;
    int mload = mrow < M ? mrow : M - 1;  // clamp; stores guarded
    const float* zrow = Z + (long)mload * 128;

    float4v acc[8];
    #pragma unroll
    for (int nt = 0; nt < 8; ++nt) acc[nt] = (float4v)(0.0f);

    #pragma unroll
    for (int c = 0; c < 4; ++c) {
        const float4v* pa = (const float4v*)(zrow + c * 32 + quad * 8);
        float4v a0 = pa[0], a1 = pa[1];
        fp16x2 p[4];
        p[0] = __builtin_amdgcn_cvt_pkrtz(a0[0], a0[1]);
        p[1] = __builtin_amdgcn_cvt_pkrtz(a0[2], a0[3]);
        p[2] = __builtin_amdgcn_cvt_pkrtz(a1[0], a1[1]);
        p[3] = __builtin_amdgcn_cvt_pkrtz(a1[2], a1[3]);
        half8v af;
        __builtin_memcpy(&af, &p[0], 16);
        const int ch = c * 4 + quad;
        #pragma unroll
        for (int nt = 0; nt < 8; ++nt) {
            const int n = l16 * 8 + nt;
            const half8v* pb = (const half8v*)&ldsW[n * 16 + (ch ^ (l16 & 7))];
            acc[nt] = __builtin_amdgcn_mfma_f32_16x16x32_f16(af, *pb, acc[nt], 0, 0, 0);
        }
    }

    float bv[8];
    if (addB) {
        const float4v* pb1 = (const float4v*)(b1 + l16 * 8);
        float4v x0 = pb1[0], x1 = pb1[1];
        bv[0]=x0[0]; bv[1]=x0[1]; bv[2]=x0[2]; bv[3]=x0[3];
        bv[4]=x1[0]; bv[5]=x1[1]; bv[6]=x1[2]; bv[7]=x1[3];
    } else {
        #pragma unroll
        for (int i = 0; i < 8; ++i) bv[i] = 0.0f;
    }

    const int rbase = m0 + wave * 16 + quad * 4;
    #pragma unroll
    for (int r = 0; r < 4; ++r) {
        int rr = rbase + r;
        if (rr < M) {
            half8v o;
            #pragma unroll
            for (int nt = 0; nt < 8; ++nt) o[nt] = (_Float16)(acc[nt][r] + bv[nt]);
            *(half8v*)&U[(long)rr * 128 + l16 * 8] = o;
        }
    }
}

// ---- Kernel B1: bucket edges by row range into (rcB, pos) with 8x-replicated
// counters: block with bid%8==p appends to subsegment (bucket*8+p). Per-address
// device-atomic chain length 977 -> ~122. (r,c) packed in a long. ----
__global__ __launch_bounds__(256) void bucket_scatter(
    const int* __restrict__ row, const int* __restrict__ col,
    long* __restrict__ rcB, int* __restrict__ pos,
    int* __restrict__ cnt, int E, float scale)
{
    __shared__ int hist[NB], base[NB], hist2[NB];
    const int t = threadIdx.x;
    const int rep = blockIdx.x & (NR - 1);
    if (t < NB) { hist[t] = 0; hist2[t] = 0; }
    __syncthreads();
    const long e0 = (long)blockIdx.x * 1024 + t;
    int r[4], c[4], bk[4];
    bool v[4];
    #pragma unroll
    for (int k = 0; k < 4; ++k) {
        long e = e0 + k * 256;
        v[k] = e < (long)E;
        long ee = v[k] ? e : 0;
        r[k] = __builtin_nontemporal_load(&row[ee]);
        c[k] = __builtin_nontemporal_load(&col[ee]);
        int b = (int)((float)r[k] * scale);
        bk[k] = b > NB - 1 ? NB - 1 : b;
        if (v[k]) atomicAdd(&hist[bk[k]], 1);
    }
    __syncthreads();
    if (t < NB) base[t] = atomicAdd(&cnt[t * NR + rep], hist[t]);
    __syncthreads();
    #pragma unroll
    for (int k = 0; k < 4; ++k) {
        if (!v[k]) continue;
        int o = atomicAdd(&hist2[bk[k]], 1);
        int slot = base[bk[k]] + o;
        long e = e0 + k * 256;
        int p = -1;
        if (slot < CAPS) {
            int g = (bk[k] * NR + rep) * CAPS + slot;
            long packed = ((long)(unsigned)r[k]) | (((long)(unsigned)c[k]) << 32);
            __builtin_nontemporal_store(packed, &rcB[g]);
            p = g;
        }
        __builtin_nontemporal_store(p, &pos[e]);   // coalesced
    }
}

// ---- Kernel B2: gather + relu-dot. XCD x (= bid%8) owns contiguous buckets
// [8x, 8x+8), swept SERIALLY (live us window ~400KB; uc gets L2 residue).
// Local block l = bid>>3: subsegment p = l&7, worker w = l>>3 (32 workers x
// 32 edges/iter, stride 1024). outB written CONTIGUOUS per subsegment. ----
__global__ __launch_bounds__(256) void edge_bucket(
    const long* __restrict__ rcB, const int* __restrict__ cnt,
    const _Float16* __restrict__ us, const _Float16* __restrict__ uc,
    const _Float16* __restrict__ w2h, const float* __restrict__ b2,
    float* __restrict__ outB)
{
    const int t = threadIdx.x, sub = t & 7;
    const int x = blockIdx.x & 7;               // XCD (blockIdx%8 heuristic)
    const int l = blockIdx.x >> 3;              // 0..255 local block on XCD
    const int p = l & 7;                        // subsegment
    const int w = l >> 3;                       // 0..31 worker in subsegment

    const uint4* pw = (const uint4*)(w2h + sub * 16);
    uint4 w0 = pw[0], w1 = pw[1];
    half2v W[8];
    *(uint4*)&W[0] = w0; *(uint4*)&W[4] = w1;
    const float bb = b2[0];
    const half2v zero = {(_Float16)0, (_Float16)0};

    #pragma unroll 1
    for (int bl = 0; bl < NB / 8; ++bl) {       // serial bucket sweep
        const int b = x * (NB / 8) + bl;
        const int ss = b * NR + p;
        int n = cnt[ss]; n = n < CAPS ? n : CAPS;
        const int seg = ss * CAPS;
        #pragma unroll 1
        for (int i0 = w * 32; i0 < n; i0 += 32 * 32) {
            int i = i0 + (t >> 3);
            bool act = i < n;
            int ii = act ? i : 0;
            long rc = __builtin_nontemporal_load(&rcB[seg + ii]);
            int r = (int)(rc & 0xffffffffL);
            int c = (int)(rc >> 32);
            const uint4* pa = (const uint4*)(us + (long)r * 128 + sub * 16);
            const uint4* pb = (const uint4*)(uc + (long)c * 128 + sub * 16);
            uint4 a0 = pa[0], a1 = pa[1];
            uint4 c0 = pb[0], c1 = pb[1];
            half2v A[8], B[8];
            *(uint4*)&A[0] = a0; *(uint4*)&A[4] = a1;
            *(uint4*)&B[0] = c0; *(uint4*)&B[4] = c1;
            float s = 0.0f;
            #pragma unroll
            for (int q = 0; q < 8; ++q) {
                half2v h = A[q] + B[q];                   // v_pk_add_f16
                h = __builtin_elementwise_max(h, zero);   // v_pk_max_f16
                s += (float)h[0] * (float)W[q][0];
                s += (float)h[1] * (float)W[q][1];
            }
            s += __shfl_xor(s, 1);
            s += __shfl_xor(s, 2);
            s += __shfl_xor(s, 4);
            if (sub == 0 && act) outB[seg + i] = s + bb;  // coalesced, L2-merged
        }
    }
}

// ---- Kernel B3: out[e] = outB[pos[e]] (outB footprint 4.5MB -> cache-served).
// pos<0 (statistically-never overflow): compute inline — u tables are ready. ----
__global__ __launch_bounds__(256) void unscatter(
    const int* __restrict__ pos, const float* __restrict__ outB,
    const int* __restrict__ row, const int* __restrict__ col,
    const _Float16* __restrict__ us, const _Float16* __restrict__ uc,
    const _Float16* __restrict__ w2h, const float* __restrict__ b2,
    float* __restrict__ out, int E)
{
    const int t = threadIdx.x;
    #pragma unroll
    for (int k = 0; k < 4; ++k) {
        long e = (long)blockIdx.x * 1024 + k * 256 + t;
        if (e >= (long)E) return;
        int p = __builtin_nontemporal_load(&pos[e]);
        float s;
        if (p >= 0) {
            s = outB[p];
        } else {
            int r = row[e], c = col[e];
            s = b2[0];
            for (int kk = 0; kk < 128; ++kk) {
                float h = (float)us[(long)r * 128 + kk] + (float)uc[(long)c * 128 + kk];
                s += fmaxf(h, 0.0f) * (float)w2h[kk];
            }
        }
        __builtin_nontemporal_store(s, &out[e]);   // coalesced
    }
}

// ---- Fallback: original direct edge kernel (used if workspace too small) ----
__global__ __launch_bounds__(256) void edge_kernel(
    const int* __restrict__ row, const int* __restrict__ col,
    const _Float16* __restrict__ us, const _Float16* __restrict__ uc,
    const _Float16* __restrict__ w2h, const float* __restrict__ b2,
    float* __restrict__ out, int E)
{
    const int t = threadIdx.x;
    const int sub = t & 7;
    long e = (long)blockIdx.x * 32 + (t >> 3);
    if (e >= E) return;
    int r = row[e], c = col[e];

    const uint4* pa = (const uint4*)(us  + (long)r * 128 + sub * 16);
    const uint4* pb = (const uint4*)(uc  + (long)c * 128 + sub * 16);
    const uint4* pw = (const uint4*)(w2h + sub * 16);
    uint4 a0 = pa[0], a1 = pa[1];
    uint4 c0 = pb[0], c1 = pb[1];
    uint4 w0 = pw[0], w1 = pw[1];

    half2v A[8], B[8], W[8];
    *(uint4*)&A[0] = a0; *(uint4*)&A[4] = a1;
    *(uint4*)&B[0] = c0; *(uint4*)&B[4] = c1;
    *(uint4*)&W[0] = w0; *(uint4*)&W[4] = w1;

    const half2v zero = {(_Float16)0, (_Float16)0};
    float s = 0.0f;
    #pragma unroll
    for (int i = 0; i < 8; ++i) {
        half2v h = A[i] + B[i];
        h = __builtin_elementwise_max(h, zero);
        s += (float)h[0] * (float)W[i][0];
        s += (float)h[1] * (float)W[i][1];
    }
    s += __shfl_xor(s, 1);
    s += __shfl_xor(s, 2);
    s += __shfl_xor(s, 4);
    if (sub == 0) out[e] = s + b2[0];
}

extern "C" void kernel_launch(void* const* d_in, const int* in_sizes, int n_in,
                              void* d_out, int out_size, void* d_ws, size_t ws_size,
                              hipStream_t stream) {
    const float* zs  = (const float*)d_in[0];
    const float* zc  = (const float*)d_in[1];
    const int*   row = (const int*)d_in[2];
    const int*   col = (const int*)d_in[3];
    const float* W1  = (const float*)d_in[4];
    const float* b1  = (const float*)d_in[5];
    const float* W2  = (const float*)d_in[6];
    const float* b2  = (const float*)d_in[7];
    float* out = (float*)d_out;

    const int Ms = in_sizes[0] / 128;   // 100000
    const int Mc = in_sizes[1] / 128;   // 20000
    const int E  = in_sizes[2];         // 1000000

    // workspace layout (256B-aligned chunks)
    char* wsb = (char*)d_ws;
    _Float16* Wt  = (_Float16*)wsb;                      // 64 KiB
    _Float16* w2h = (_Float16*)(wsb + 65536);            // 256 B
    int*      cnt = (int*)(wsb + 65792);                 // 2 KiB (512 ints)
    size_t off = 67840;
    _Float16* us = (_Float16*)(wsb + off);  off += (size_t)Ms * 256;  // f16
    _Float16* uc = (_Float16*)(wsb + off);  off += (size_t)Mc * 256;
    long*  rcB  = (long*)(wsb + off);  off += (size_t)NB * NR * CAPS * 8;
    int*   pos  = (int*)(wsb + off);   off += (size_t)E * 4;
    float* outB = (float*)(wsb + off); off += (size_t)NB * NR * CAPS * 4;
    const bool bucketed = (off <= ws_size);

    const int nbs = (Ms + 63) / 64, nbc = (Mc + 63) / 64;

    conv_w<<<9, 256, 0, stream>>>(W1, W2, Wt, w2h, cnt);
    gemm_u<<<nbs + nbc, 256, 0, stream>>>(zs, zc, Wt, b1, us, uc, Ms, Mc, nbs);
    if (bucketed) {
        bucket_scatter<<<(E + 1023) / 1024, 256, 0, stream>>>(
            row, col, rcB, pos, cnt, E, (float)NB / (float)Ms);
        edge_bucket<<<2048, 256, 0, stream>>>(rcB, cnt, us, uc, w2h, b2, outB);
        unscatter<<<(E + 1023) / 1024, 256, 0, stream>>>(
            pos, outB, row, col, us, uc, w2h, b2, out, E);
    } else {
        edge_kernel<<<(E + 31) / 32, 256, 0, stream>>>(row, col, us, uc, w2h, b2, out, E);
    }
    (void)n_in; (void)out_size;
}

// Round 7
// 189.078 us; speedup vs baseline: 1.0462x; 1.0061x over previous
//
#include <hip/hip_runtime.h>
#include <hip/hip_bf16.h>
#include <hip/hip_fp16.h>

// out[e] = relu(z_s[row[e]]@W1_top + z_c[col[e]]@W1_bot + b1) @ W2 + b2
// u_s = z_s@W1_top + b1, u_c = z_c@W1_bot (both f16 in ws); per edge:
// out = sum_k relu(u_s[row][k]+u_c[col][k]) * W2[k] + b2.
//
// R7: serial-sweep bucketing (read side validated: FETCH = 84MB = compulsory).
// New: (1) bucket_scatter FUSED into the gemm launch (independent inputs ->
// overlapped); (2) (r,c) packed into 32 bits (rcB 16->4.7MB); (3) ILP-2 in
// edge_bucket (latency-vs-path diagnostic); (4) NR=16 counter replicas.

typedef _Float16 half2v __attribute__((ext_vector_type(2)));
typedef _Float16 half8v __attribute__((ext_vector_type(8)));
typedef __fp16   fp16x2 __attribute__((ext_vector_type(2)));
typedef float    float4v __attribute__((ext_vector_type(4)));

#define NB   64     // row-range buckets; XCD x owns [8x, 8x+8)
#define NR   16     // counter replicas = subsegments per bucket (by sb%16)
#define CAPS 1152   // per-subsegment cap; mean 977, sigma ~31 -> +5.6 sigma

// ---- Kernel 1: W1 [256,128] fp32 -> Wt[half][n][k] f16 (LDS transpose), W2 -> f16 ----
__global__ __launch_bounds__(256) void conv_w(const float* __restrict__ W1,
                                              const float* __restrict__ W2,
                                              _Float16* __restrict__ Wt,
                                              _Float16* __restrict__ w2h,
                                              int* __restrict__ cnt) {
    int b = blockIdx.x, t = threadIdx.x;
    if (b == 8) {
        if (t < 128) w2h[t] = (_Float16)W2[t];
        for (int i = t; i < NB * NR; i += 256) cnt[i] = 0;   // re-zero each replay
        return;
    }
    __shared__ _Float16 lds[32][136];
    int h = b >> 2, n0 = (b & 3) * 32;
    for (int i = 0; i < 16; ++i) {
        int idx = i * 256 + t;            // 4096 = 128k x 32n
        int k = idx >> 5, nn = idx & 31;
        lds[nn][k] = (_Float16)W1[(h * 128 + k) * 128 + n0 + nn];
    }
    __syncthreads();
    for (int j = 0; j < 2; ++j) {
        int idx = j * 256 + t;            // 512 = 32n x 16 chunks
        int nn = idx >> 4, kc = idx & 15;
        half8v v;
        #pragma unroll
        for (int q = 0; q < 8; ++q) v[q] = lds[nn][kc * 8 + q];
        *(half8v*)&Wt[((h * 128 + n0 + nn) * 128) + kc * 8] = v;
    }
}

// ---- Kernel 2 (fused): blocks [0,G) = U_s/U_c GEMM; blocks [G,G+SB) =
// bucket_scatter. Independent inputs -> scatter hides under gemm. ----
__global__ __launch_bounds__(256) void gemm_scatter(
    const float* __restrict__ Zs, const float* __restrict__ Zc,
    const _Float16* __restrict__ Wt, const float* __restrict__ b1,
    _Float16* __restrict__ Us, _Float16* __restrict__ Uc,
    int Ms, int Mc, int nbs, int G,
    const int* __restrict__ row, const int* __restrict__ col,
    unsigned* __restrict__ rcB, int* __restrict__ pos,
    int* __restrict__ cnt, int E, float scale)
{
    __shared__ uint4 ldsW[2048];          // gemm: 128x16 swizzled chunks (32 KiB)
    const int t = threadIdx.x;

    if ((int)blockIdx.x >= G) {
        // ---------------- scatter path ----------------
        const int sb = blockIdx.x - G;
        int* hist  = (int*)ldsW;          // alias LDS
        int* base  = hist + NB;
        int* hist2 = hist + 2 * NB;
        const int rep = sb & (NR - 1);
        if (t < NB) { hist[t] = 0; hist2[t] = 0; }
        __syncthreads();
        const long e0 = (long)sb * 1024 + t;
        int r[4], c[4], bk[4];
        bool v[4];
        #pragma unroll
        for (int k = 0; k < 4; ++k) {
            long e = e0 + k * 256;
            v[k] = e < (long)E;
            long ee = v[k] ? e : 0;
            r[k] = __builtin_nontemporal_load(&row[ee]);
            c[k] = __builtin_nontemporal_load(&col[ee]);
            int b = (int)((float)r[k] * scale);
            bk[k] = b > NB - 1 ? NB - 1 : b;
            if (v[k]) atomicAdd(&hist[bk[k]], 1);
        }
        __syncthreads();
        if (t < NB) base[t] = atomicAdd(&cnt[t * NR + rep], hist[t]);
        __syncthreads();
        #pragma unroll
        for (int k = 0; k < 4; ++k) {
            if (!v[k]) continue;
            int o = atomicAdd(&hist2[bk[k]], 1);
            int slot = base[bk[k]] + o;
            long e = e0 + k * 256;
            int p = -1;
            if (slot < CAPS) {
                int g = (bk[k] * NR + rep) * CAPS + slot;
                unsigned packed = (unsigned)r[k] | ((unsigned)c[k] << 17);
                __builtin_nontemporal_store(packed, &rcB[g]);
                p = g;
            }
            __builtin_nontemporal_store(p, &pos[e]);   // coalesced
        }
        return;
    }

    // ---------------- gemm path ----------------
    const int bid = blockIdx.x;
    const float* Z; _Float16* U; const _Float16* W; int M, m0, addB;
    if (bid < nbs) { Z = Zs; U = Us; M = Ms; m0 = bid * 64;         W = Wt;         addB = 1; }
    else           { Z = Zc; U = Uc; M = Mc; m0 = (bid - nbs) * 64; W = Wt + 16384; addB = 0; }

    const uint4* Wv = (const uint4*)W;    // [n][16 chunks]
    #pragma unroll
    for (int i = 0; i < 8; ++i) {
        int j = i * 256 + t;              // 2048
        int n = j >> 4, ch = j & 15;
        ldsW[n * 16 + (ch ^ ((n >> 3) & 7))] = Wv[j];
    }
    __syncthreads();

    const int wave = t >> 6, lane = t & 63, quad = lane >> 4, l16 = lane & 15;
    int mrow = m0 + wave * 16 + l16;
    int mload = mrow < M ? mrow : M - 1;  // clamp; stores guarded
    const float* zrow = Z + (long)mload * 128;

    float4v acc[8];
    #pragma unroll
    for (int nt = 0; nt < 8; ++nt) acc[nt] = (float4v)(0.0f);

    #pragma unroll
    for (int c = 0; c < 4; ++c) {
        const float4v* pa = (const float4v*)(zrow + c * 32 + quad * 8);
        float4v a0 = pa[0], a1 = pa[1];
        fp16x2 p[4];
        p[0] = __builtin_amdgcn_cvt_pkrtz(a0[0], a0[1]);
        p[1] = __builtin_amdgcn_cvt_pkrtz(a0[2], a0[3]);
        p[2] = __builtin_amdgcn_cvt_pkrtz(a1[0], a1[1]);
        p[3] = __builtin_amdgcn_cvt_pkrtz(a1[2], a1[3]);
        half8v af;
        __builtin_memcpy(&af, &p[0], 16);
        const int ch = c * 4 + quad;
        #pragma unroll
        for (int nt = 0; nt < 8; ++nt) {
            const int n = l16 * 8 + nt;
            const half8v* pb = (const half8v*)&ldsW[n * 16 + (ch ^ (l16 & 7))];
            acc[nt] = __builtin_amdgcn_mfma_f32_16x16x32_f16(af, *pb, acc[nt], 0, 0, 0);
        }
    }

    float bv[8];
    if (addB) {
        const float4v* pb1 = (const float4v*)(b1 + l16 * 8);
        float4v x0 = pb1[0], x1 = pb1[1];
        bv[0]=x0[0]; bv[1]=x0[1]; bv[2]=x0[2]; bv[3]=x0[3];
        bv[4]=x1[0]; bv[5]=x1[1]; bv[6]=x1[2]; bv[7]=x1[3];
    } else {
        #pragma unroll
        for (int i = 0; i < 8; ++i) bv[i] = 0.0f;
    }

    const int rbase = m0 + wave * 16 + quad * 4;
    #pragma unroll
    for (int r = 0; r < 4; ++r) {
        int rr = rbase + r;
        if (rr < M) {
            half8v o;
            #pragma unroll
            for (int nt = 0; nt < 8; ++nt) o[nt] = (_Float16)(acc[nt][r] + bv[nt]);
            *(half8v*)&U[(long)rr * 128 + l16 * 8] = o;
        }
    }
}

// ---- Kernel B2: gather + relu-dot, ILP-2. XCD x (= bid%8) owns contiguous
// buckets [8x,8x+8), swept SERIALLY. Local block l=bid>>3: subsegment p=l&15,
// worker w=l>>4; per iteration each thread handles edges i and i+32 (64 edges
// per block-iter, 8 gathers in flight/thread). outB coalesced. ----
__global__ __launch_bounds__(256) void edge_bucket(
    const unsigned* __restrict__ rcB, const int* __restrict__ cnt,
    const _Float16* __restrict__ us, const _Float16* __restrict__ uc,
    const _Float16* __restrict__ w2h, const float* __restrict__ b2,
    float* __restrict__ outB)
{
    const int t = threadIdx.x, sub = t & 7, tg = t >> 3;
    const int x = blockIdx.x & 7;               // XCD (blockIdx%8 heuristic)
    const int l = blockIdx.x >> 3;              // 0..255 local block on XCD
    const int p = l & (NR - 1);                 // subsegment
    const int w = l >> 4;                       // 0..15 worker in subsegment

    const uint4* pw = (const uint4*)(w2h + sub * 16);
    uint4 w0 = pw[0], w1 = pw[1];
    half2v W[8];
    *(uint4*)&W[0] = w0; *(uint4*)&W[4] = w1;
    const float bb = b2[0];
    const half2v zero = {(_Float16)0, (_Float16)0};

    #pragma unroll 1
    for (int bl = 0; bl < NB / 8; ++bl) {       // serial bucket sweep
        const int b = x * (NB / 8) + bl;
        const int ss = b * NR + p;
        int n = cnt[ss]; n = n < CAPS ? n : CAPS;
        const int seg = ss * CAPS;
        #pragma unroll 1
        for (int i0 = w * 64; i0 < n; i0 += 16 * 64) {
            int i  = i0 + tg;
            int i2 = i + 32;
            bool a0v = i < n, a1v = i2 < n;
            int ii  = a0v ? i  : 0;
            int ii2 = a1v ? i2 : 0;
            unsigned p0 = __builtin_nontemporal_load(&rcB[seg + ii]);
            unsigned p1 = __builtin_nontemporal_load(&rcB[seg + ii2]);
            int r0 = p0 & 0x1FFFF, c0 = p0 >> 17;
            int r1 = p1 & 0x1FFFF, c1 = p1 >> 17;
            const uint4* pa0 = (const uint4*)(us + (long)r0 * 128 + sub * 16);
            const uint4* pb0 = (const uint4*)(uc + (long)c0 * 128 + sub * 16);
            const uint4* pa1 = (const uint4*)(us + (long)r1 * 128 + sub * 16);
            const uint4* pb1 = (const uint4*)(uc + (long)c1 * 128 + sub * 16);
            // all 8 gathers issued before any compute
            uint4 a00 = pa0[0], a01 = pa0[1];
            uint4 b00 = pb0[0], b01 = pb0[1];
            uint4 a10 = pa1[0], a11 = pa1[1];
            uint4 b10 = pb1[0], b11 = pb1[1];
            half2v A0[8], B0[8], A1[8], B1[8];
            *(uint4*)&A0[0] = a00; *(uint4*)&A0[4] = a01;
            *(uint4*)&B0[0] = b00; *(uint4*)&B0[4] = b01;
            *(uint4*)&A1[0] = a10; *(uint4*)&A1[4] = a11;
            *(uint4*)&B1[0] = b10; *(uint4*)&B1[4] = b11;
            float s0 = 0.0f, s1 = 0.0f;
            #pragma unroll
            for (int q = 0; q < 8; ++q) {
                half2v h0 = A0[q] + B0[q];                 // v_pk_add_f16
                half2v h1 = A1[q] + B1[q];
                h0 = __builtin_elementwise_max(h0, zero);  // v_pk_max_f16
                h1 = __builtin_elementwise_max(h1, zero);
                s0 += (float)h0[0] * (float)W[q][0];
                s0 += (float)h0[1] * (float)W[q][1];
                s1 += (float)h1[0] * (float)W[q][0];
                s1 += (float)h1[1] * (float)W[q][1];
            }
            s0 += __shfl_xor(s0, 1);
            s1 += __shfl_xor(s1, 1);
            s0 += __shfl_xor(s0, 2);
            s1 += __shfl_xor(s1, 2);
            s0 += __shfl_xor(s0, 4);
            s1 += __shfl_xor(s1, 4);
            if (sub == 0) {
                if (a0v) outB[seg + i]  = s0 + bb;   // coalesced, L2-merged
                if (a1v) outB[seg + i2] = s1 + bb;
            }
        }
    }
}

// ---- Kernel B3: out[e] = outB[pos[e]] (outB 4.7MB -> mostly cache-served).
// pos<0 (statistically-never overflow): compute inline — u tables ready. ----
__global__ __launch_bounds__(256) void unscatter(
    const int* __restrict__ pos, const float* __restrict__ outB,
    const int* __restrict__ row, const int* __restrict__ col,
    const _Float16* __restrict__ us, const _Float16* __restrict__ uc,
    const _Float16* __restrict__ w2h, const float* __restrict__ b2,
    float* __restrict__ out, int E)
{
    const int t = threadIdx.x;
    #pragma unroll
    for (int k = 0; k < 4; ++k) {
        long e = (long)blockIdx.x * 1024 + k * 256 + t;
        if (e >= (long)E) return;
        int p = __builtin_nontemporal_load(&pos[e]);
        float s;
        if (p >= 0) {
            s = outB[p];
        } else {
            int r = row[e], c = col[e];
            s = b2[0];
            for (int kk = 0; kk < 128; ++kk) {
                float h = (float)us[(long)r * 128 + kk] + (float)uc[(long)c * 128 + kk];
                s += fmaxf(h, 0.0f) * (float)w2h[kk];
            }
        }
        __builtin_nontemporal_store(s, &out[e]);   // coalesced
    }
}

// ---- Fallback: direct edge kernel (used if workspace too small) ----
__global__ __launch_bounds__(256) void edge_kernel(
    const int* __restrict__ row, const int* __restrict__ col,
    const _Float16* __restrict__ us, const _Float16* __restrict__ uc,
    const _Float16* __restrict__ w2h, const float* __restrict__ b2,
    float* __restrict__ out, int E)
{
    const int t = threadIdx.x;
    const int sub = t & 7;
    long e = (long)blockIdx.x * 32 + (t >> 3);
    if (e >= E) return;
    int r = row[e], c = col[e];

    const uint4* pa = (const uint4*)(us  + (long)r * 128 + sub * 16);
    const uint4* pb = (const uint4*)(uc  + (long)c * 128 + sub * 16);
    const uint4* pw = (const uint4*)(w2h + sub * 16);
    uint4 a0 = pa[0], a1 = pa[1];
    uint4 c0 = pb[0], c1 = pb[1];
    uint4 w0 = pw[0], w1 = pw[1];

    half2v A[8], B[8], W[8];
    *(uint4*)&A[0] = a0; *(uint4*)&A[4] = a1;
    *(uint4*)&B[0] = c0; *(uint4*)&B[4] = c1;
    *(uint4*)&W[0] = w0; *(uint4*)&W[4] = w1;

    const half2v zero = {(_Float16)0, (_Float16)0};
    float s = 0.0f;
    #pragma unroll
    for (int i = 0; i < 8; ++i) {
        half2v h = A[i] + B[i];
        h = __builtin_elementwise_max(h, zero);
        s += (float)h[0] * (float)W[i][0];
        s += (float)h[1] * (float)W[i][1];
    }
    s += __shfl_xor(s, 1);
    s += __shfl_xor(s, 2);
    s += __shfl_xor(s, 4);
    if (sub == 0) out[e] = s + b2[0];
}

extern "C" void kernel_launch(void* const* d_in, const int* in_sizes, int n_in,
                              void* d_out, int out_size, void* d_ws, size_t ws_size,
                              hipStream_t stream) {
    const float* zs  = (const float*)d_in[0];
    const float* zc  = (const float*)d_in[1];
    const int*   row = (const int*)d_in[2];
    const int*   col = (const int*)d_in[3];
    const float* W1  = (const float*)d_in[4];
    const float* b1  = (const float*)d_in[5];
    const float* W2  = (const float*)d_in[6];
    const float* b2  = (const float*)d_in[7];
    float* out = (float*)d_out;

    const int Ms = in_sizes[0] / 128;   // 100000
    const int Mc = in_sizes[1] / 128;   // 20000
    const int E  = in_sizes[2];         // 1000000

    // workspace layout (256B-aligned chunks)
    char* wsb = (char*)d_ws;
    _Float16* Wt  = (_Float16*)wsb;                      // 64 KiB
    _Float16* w2h = (_Float16*)(wsb + 65536);            // 256 B
    int*      cnt = (int*)(wsb + 65792);                 // 4 KiB (1024 ints)
    size_t off = 69888;
    _Float16* us = (_Float16*)(wsb + off);  off += (size_t)Ms * 256;  // f16
    _Float16* uc = (_Float16*)(wsb + off);  off += (size_t)Mc * 256;
    unsigned* rcB = (unsigned*)(wsb + off); off += (size_t)NB * NR * CAPS * 4;
    int*   pos  = (int*)(wsb + off);   off += (size_t)E * 4;
    float* outB = (float*)(wsb + off); off += (size_t)NB * NR * CAPS * 4;
    const bool bucketed = (off <= ws_size);

    const int nbs = (Ms + 63) / 64, nbc = (Mc + 63) / 64;
    const int G = nbs + nbc;
    const int SB = bucketed ? (E + 1023) / 1024 : 0;

    conv_w<<<9, 256, 0, stream>>>(W1, W2, Wt, w2h, cnt);
    gemm_scatter<<<G + SB, 256, 0, stream>>>(
        zs, zc, Wt, b1, us, uc, Ms, Mc, nbs, G,
        row, col, rcB, pos, cnt, E, (float)NB / (float)Ms);
    if (bucketed) {
        edge_bucket<<<2048, 256, 0, stream>>>(rcB, cnt, us, uc, w2h, b2, outB);
        unscatter<<<(E + 1023) / 1024, 256, 0, stream>>>(
            pos, outB, row, col, us, uc, w2h, b2, out, E);
    } else {
        edge_kernel<<<(E + 31) / 32, 256, 0, stream>>>(row, col, us, uc, w2h, b2, out, E);
    }
    (void)n_in; (void)out_size;
}

// Round 8
// 176.130 us; speedup vs baseline: 1.1232x; 1.0735x over previous
//
#include <hip/hip_runtime.h>
#include <hip/hip_bf16.h>
#include <hip/hip_fp16.h>

// out[e] = relu(z_s[row[e]]@W1_top + z_c[col[e]]@W1_bot + b1) @ W2 + b2
// u_s = z_s@W1_top + b1, u_c = z_c@W1_bot (both f16 in ws); per edge:
// out = sum_k relu(u_s[row][k]+u_c[col][k]) * W2[k] + b2.
//
// R8: serial-sweep bucketing (read side validated: FETCH = 84MB = compulsory).
// Fixes vs R7 (from counters: WRITE 77MB, atomic-chain critical path):
// (1) NR=64 counter replicas -> per-address device-atomic chains 61 -> ~15;
// (2) rcB stores REGULAR (R7's NT scattered 4B stores bypassed L2-merge ->
//     ~40MB partial-line write amplification);
// (3) gemm and scatter de-fused (fusion serialized anyway + LDS-capped occ).

typedef _Float16 half2v __attribute__((ext_vector_type(2)));
typedef _Float16 half8v __attribute__((ext_vector_type(8)));
typedef __fp16   fp16x2 __attribute__((ext_vector_type(2)));
typedef float    float4v __attribute__((ext_vector_type(4)));

#define NB   64     // row-range buckets; XCD x owns [8x, 8x+8)
#define NR   64     // counter replicas = subsegments per bucket (by blk%64)
#define CAPS 384    // per-subsegment cap; mean <=256, sigma ~16 -> +8 sigma

// ---- Kernel 1: W1 [256,128] fp32 -> Wt[half][n][k] f16 (LDS transpose), W2 -> f16 ----
__global__ __launch_bounds__(256) void conv_w(const float* __restrict__ W1,
                                              const float* __restrict__ W2,
                                              _Float16* __restrict__ Wt,
                                              _Float16* __restrict__ w2h,
                                              int* __restrict__ cnt) {
    int b = blockIdx.x, t = threadIdx.x;
    if (b == 8) {
        if (t < 128) w2h[t] = (_Float16)W2[t];
        for (int i = t; i < NB * NR; i += 256) cnt[i] = 0;   // re-zero each replay
        return;
    }
    __shared__ _Float16 lds[32][136];
    int h = b >> 2, n0 = (b & 3) * 32;
    for (int i = 0; i < 16; ++i) {
        int idx = i * 256 + t;            // 4096 = 128k x 32n
        int k = idx >> 5, nn = idx & 31;
        lds[nn][k] = (_Float16)W1[(h * 128 + k) * 128 + n0 + nn];
    }
    __syncthreads();
    for (int j = 0; j < 2; ++j) {
        int idx = j * 256 + t;            // 512 = 32n x 16 chunks
        int nn = idx >> 4, kc = idx & 15;
        half8v v;
        #pragma unroll
        for (int q = 0; q < 8; ++q) v[q] = lds[nn][kc * 8 + q];
        *(half8v*)&Wt[((h * 128 + n0 + nn) * 128) + kc * 8] = v;
    }
}

// ---- Kernel 2: fused U_s / U_c GEMM, MFMA 16x16x32 f16, vectorized epilogue ----
__global__ __launch_bounds__(256) void gemm_u(
    const float* __restrict__ Zs, const float* __restrict__ Zc,
    const _Float16* __restrict__ Wt, const float* __restrict__ b1,
    _Float16* __restrict__ Us, _Float16* __restrict__ Uc,
    int Ms, int Mc, int nbs)
{
    __shared__ uint4 ldsW[2048];          // 128 x 16 chunks, swizzled, 32 KiB
    const int bid = blockIdx.x, t = threadIdx.x;

    const float* Z; _Float16* U; const _Float16* W; int M, m0, addB;
    if (bid < nbs) { Z = Zs; U = Us; M = Ms; m0 = bid * 64;         W = Wt;         addB = 1; }
    else           { Z = Zc; U = Uc; M = Mc; m0 = (bid - nbs) * 64; W = Wt + 16384; addB = 0; }

    const uint4* Wv = (const uint4*)W;    // [n][16 chunks]
    #pragma unroll
    for (int i = 0; i < 8; ++i) {
        int j = i * 256 + t;              // 2048
        int n = j >> 4, ch = j & 15;
        ldsW[n * 16 + (ch ^ ((n >> 3) & 7))] = Wv[j];
    }
    __syncthreads();

    const int wave = t >> 6, lane = t & 63, quad = lane >> 4, l16 = lane & 15;
    int mrow = m0 + wave * 16 + l16;
    int mload = mrow < M ? mrow : M - 1;  // clamp; stores guarded
    const float* zrow = Z + (long)mload * 128;

    float4v acc[8];
    #pragma unroll
    for (int nt = 0; nt < 8; ++nt) acc[nt] = (float4v)(0.0f);

    #pragma unroll
    for (int c = 0; c < 4; ++c) {
        const float4v* pa = (const float4v*)(zrow + c * 32 + quad * 8);
        float4v a0 = pa[0], a1 = pa[1];
        fp16x2 p[4];
        p[0] = __builtin_amdgcn_cvt_pkrtz(a0[0], a0[1]);
        p[1] = __builtin_amdgcn_cvt_pkrtz(a0[2], a0[3]);
        p[2] = __builtin_amdgcn_cvt_pkrtz(a1[0], a1[1]);
        p[3] = __builtin_amdgcn_cvt_pkrtz(a1[2], a1[3]);
        half8v af;
        __builtin_memcpy(&af, &p[0], 16);
        const int ch = c * 4 + quad;
        #pragma unroll
        for (int nt = 0; nt < 8; ++nt) {
            const int n = l16 * 8 + nt;
            const half8v* pb = (const half8v*)&ldsW[n * 16 + (ch ^ (l16 & 7))];
            acc[nt] = __builtin_amdgcn_mfma_f32_16x16x32_f16(af, *pb, acc[nt], 0, 0, 0);
        }
    }

    float bv[8];
    if (addB) {
        const float4v* pb1 = (const float4v*)(b1 + l16 * 8);
        float4v x0 = pb1[0], x1 = pb1[1];
        bv[0]=x0[0]; bv[1]=x0[1]; bv[2]=x0[2]; bv[3]=x0[3];
        bv[4]=x1[0]; bv[5]=x1[1]; bv[6]=x1[2]; bv[7]=x1[3];
    } else {
        #pragma unroll
        for (int i = 0; i < 8; ++i) bv[i] = 0.0f;
    }

    const int rbase = m0 + wave * 16 + quad * 4;
    #pragma unroll
    for (int r = 0; r < 4; ++r) {
        int rr = rbase + r;
        if (rr < M) {
            half8v o;
            #pragma unroll
            for (int nt = 0; nt < 8; ++nt) o[nt] = (_Float16)(acc[nt][r] + bv[nt]);
            *(half8v*)&U[(long)rr * 128 + l16 * 8] = o;
        }
    }
}

// ---- Kernel B1: bucket edges by row range into (rcB, pos). 64x-replicated
// counters (rep = blk%64): per-address device-atomic chains ~15 -> the base
// grab is no longer the critical path. rcB stores REGULAR (L2-merged). ----
__global__ __launch_bounds__(256) void bucket_scatter(
    const int* __restrict__ row, const int* __restrict__ col,
    unsigned* __restrict__ rcB, int* __restrict__ pos,
    int* __restrict__ cnt, int E, float scale)
{
    __shared__ int hist[NB], base[NB], hist2[NB];
    const int t = threadIdx.x;
    const int rep = blockIdx.x & (NR - 1);
    if (t < NB) { hist[t] = 0; hist2[t] = 0; }
    __syncthreads();
    const long e0 = (long)blockIdx.x * 1024 + t;
    int r[4], c[4], bk[4];
    bool v[4];
    #pragma unroll
    for (int k = 0; k < 4; ++k) {
        long e = e0 + k * 256;
        v[k] = e < (long)E;
        long ee = v[k] ? e : 0;
        r[k] = __builtin_nontemporal_load(&row[ee]);
        c[k] = __builtin_nontemporal_load(&col[ee]);
        int b = (int)((float)r[k] * scale);
        bk[k] = b > NB - 1 ? NB - 1 : b;
        if (v[k]) atomicAdd(&hist[bk[k]], 1);
    }
    __syncthreads();
    if (t < NB) base[t] = atomicAdd(&cnt[t * NR + rep], hist[t]);
    __syncthreads();
    #pragma unroll
    for (int k = 0; k < 4; ++k) {
        if (!v[k]) continue;
        int o = atomicAdd(&hist2[bk[k]], 1);
        int slot = base[bk[k]] + o;
        long e = e0 + k * 256;
        int p = -1;
        if (slot < CAPS) {
            int g = (bk[k] * NR + rep) * CAPS + slot;
            rcB[g] = (unsigned)r[k] | ((unsigned)c[k] << 17);  // regular: L2 merges
            p = g;
        }
        __builtin_nontemporal_store(p, &pos[e]);   // coalesced full lines
    }
}

// ---- Kernel B2: gather + relu-dot, ILP-2. XCD x (= bid%8) owns contiguous
// buckets [8x,8x+8), swept SERIALLY (live us window ~400KB; uc gets L2
// residue). Local block l=bid>>3: subsegment p=l&63, worker w=l>>6 (4 workers
// x 64 edges/iter, stride 256). outB coalesced per subsegment. ----
__global__ __launch_bounds__(256) void edge_bucket(
    const unsigned* __restrict__ rcB, const int* __restrict__ cnt,
    const _Float16* __restrict__ us, const _Float16* __restrict__ uc,
    const _Float16* __restrict__ w2h, const float* __restrict__ b2,
    float* __restrict__ outB)
{
    const int t = threadIdx.x, sub = t & 7, tg = t >> 3;
    const int x = blockIdx.x & 7;               // XCD (blockIdx%8 heuristic)
    const int l = blockIdx.x >> 3;              // 0..255 local block on XCD
    const int p = l & (NR - 1);                 // subsegment 0..63
    const int w = l >> 6;                       // 0..3 worker in subsegment

    const uint4* pw = (const uint4*)(w2h + sub * 16);
    uint4 w0 = pw[0], w1 = pw[1];
    half2v W[8];
    *(uint4*)&W[0] = w0; *(uint4*)&W[4] = w1;
    const float bb = b2[0];
    const half2v zero = {(_Float16)0, (_Float16)0};

    #pragma unroll 1
    for (int bl = 0; bl < NB / 8; ++bl) {       // serial bucket sweep
        const int b = x * (NB / 8) + bl;
        const int ss = b * NR + p;
        int n = cnt[ss]; n = n < CAPS ? n : CAPS;
        const int seg = ss * CAPS;
        #pragma unroll 1
        for (int i0 = w * 64; i0 < n; i0 += 4 * 64) {
            int i  = i0 + tg;
            int i2 = i + 32;
            bool a0v = i < n, a1v = i2 < n;
            int ii  = a0v ? i  : 0;
            int ii2 = a1v ? i2 : 0;
            unsigned p0 = __builtin_nontemporal_load(&rcB[seg + ii]);
            unsigned p1 = __builtin_nontemporal_load(&rcB[seg + ii2]);
            int r0 = p0 & 0x1FFFF, c0 = p0 >> 17;
            int r1 = p1 & 0x1FFFF, c1 = p1 >> 17;
            const uint4* pa0 = (const uint4*)(us + (long)r0 * 128 + sub * 16);
            const uint4* pb0 = (const uint4*)(uc + (long)c0 * 128 + sub * 16);
            const uint4* pa1 = (const uint4*)(us + (long)r1 * 128 + sub * 16);
            const uint4* pb1 = (const uint4*)(uc + (long)c1 * 128 + sub * 16);
            // all 8 gathers issued before any compute
            uint4 a00 = pa0[0], a01 = pa0[1];
            uint4 b00 = pb0[0], b01 = pb0[1];
            uint4 a10 = pa1[0], a11 = pa1[1];
            uint4 b10 = pb1[0], b11 = pb1[1];
            half2v A0[8], B0[8], A1[8], B1[8];
            *(uint4*)&A0[0] = a00; *(uint4*)&A0[4] = a01;
            *(uint4*)&B0[0] = b00; *(uint4*)&B0[4] = b01;
            *(uint4*)&A1[0] = a10; *(uint4*)&A1[4] = a11;
            *(uint4*)&B1[0] = b10; *(uint4*)&B1[4] = b11;
            float s0 = 0.0f, s1 = 0.0f;
            #pragma unroll
            for (int q = 0; q < 8; ++q) {
                half2v h0 = A0[q] + B0[q];                 // v_pk_add_f16
                half2v h1 = A1[q] + B1[q];
                h0 = __builtin_elementwise_max(h0, zero);  // v_pk_max_f16
                h1 = __builtin_elementwise_max(h1, zero);
                s0 += (float)h0[0] * (float)W[q][0];
                s0 += (float)h0[1] * (float)W[q][1];
                s1 += (float)h1[0] * (float)W[q][0];
                s1 += (float)h1[1] * (float)W[q][1];
            }
            s0 += __shfl_xor(s0, 1);
            s1 += __shfl_xor(s1, 1);
            s0 += __shfl_xor(s0, 2);
            s1 += __shfl_xor(s1, 2);
            s0 += __shfl_xor(s0, 4);
            s1 += __shfl_xor(s1, 4);
            if (sub == 0) {
                if (a0v) outB[seg + i]  = s0 + bb;   // coalesced, L2-merged
                if (a1v) outB[seg + i2] = s1 + bb;
            }
        }
    }
}

// ---- Kernel B3: out[e] = outB[pos[e]] (outB 6.3MB -> mostly cache-served).
// pos<0 (statistically-never overflow): compute inline — u tables ready. ----
__global__ __launch_bounds__(256) void unscatter(
    const int* __restrict__ pos, const float* __restrict__ outB,
    const int* __restrict__ row, const int* __restrict__ col,
    const _Float16* __restrict__ us, const _Float16* __restrict__ uc,
    const _Float16* __restrict__ w2h, const float* __restrict__ b2,
    float* __restrict__ out, int E)
{
    const int t = threadIdx.x;
    #pragma unroll
    for (int k = 0; k < 4; ++k) {
        long e = (long)blockIdx.x * 1024 + k * 256 + t;
        if (e >= (long)E) return;
        int p = __builtin_nontemporal_load(&pos[e]);
        float s;
        if (p >= 0) {
            s = outB[p];
        } else {
            int r = row[e], c = col[e];
            s = b2[0];
            for (int kk = 0; kk < 128; ++kk) {
                float h = (float)us[(long)r * 128 + kk] + (float)uc[(long)c * 128 + kk];
                s += fmaxf(h, 0.0f) * (float)w2h[kk];
            }
        }
        __builtin_nontemporal_store(s, &out[e]);   // coalesced
    }
}

// ---- Fallback: direct edge kernel (used if workspace too small) ----
__global__ __launch_bounds__(256) void edge_kernel(
    const int* __restrict__ row, const int* __restrict__ col,
    const _Float16* __restrict__ us, const _Float16* __restrict__ uc,
    const _Float16* __restrict__ w2h, const float* __restrict__ b2,
    float* __restrict__ out, int E)
{
    const int t = threadIdx.x;
    const int sub = t & 7;
    long e = (long)blockIdx.x * 32 + (t >> 3);
    if (e >= E) return;
    int r = row[e], c = col[e];

    const uint4* pa = (const uint4*)(us  + (long)r * 128 + sub * 16);
    const uint4* pb = (const uint4*)(uc  + (long)c * 128 + sub * 16);
    const uint4* pw = (const uint4*)(w2h + sub * 16);
    uint4 a0 = pa[0], a1 = pa[1];
    uint4 c0 = pb[0], c1 = pb[1];
    uint4 w0 = pw[0], w1 = pw[1];

    half2v A[8], B[8], W[8];
    *(uint4*)&A[0] = a0; *(uint4*)&A[4] = a1;
    *(uint4*)&B[0] = c0; *(uint4*)&B[4] = c1;
    *(uint4*)&W[0] = w0; *(uint4*)&W[4] = w1;

    const half2v zero = {(_Float16)0, (_Float16)0};
    float s = 0.0f;
    #pragma unroll
    for (int i = 0; i < 8; ++i) {
        half2v h = A[i] + B[i];
        h = __builtin_elementwise_max(h, zero);
        s += (float)h[0] * (float)W[i][0];
        s += (float)h[1] * (float)W[i][1];
    }
    s += __shfl_xor(s, 1);
    s += __shfl_xor(s, 2);
    s += __shfl_xor(s, 4);
    if (sub == 0) out[e] = s + b2[0];
}

extern "C" void kernel_launch(void* const* d_in, const int* in_sizes, int n_in,
                              void* d_out, int out_size, void* d_ws, size_t ws_size,
                              hipStream_t stream) {
    const float* zs  = (const float*)d_in[0];
    const float* zc  = (const float*)d_in[1];
    const int*   row = (const int*)d_in[2];
    const int*   col = (const int*)d_in[3];
    const float* W1  = (const float*)d_in[4];
    const float* b1  = (const float*)d_in[5];
    const float* W2  = (const float*)d_in[6];
    const float* b2  = (const float*)d_in[7];
    float* out = (float*)d_out;

    const int Ms = in_sizes[0] / 128;   // 100000
    const int Mc = in_sizes[1] / 128;   // 20000
    const int E  = in_sizes[2];         // 1000000

    // workspace layout (256B-aligned chunks)
    char* wsb = (char*)d_ws;
    _Float16* Wt  = (_Float16*)wsb;                      // 64 KiB
    _Float16* w2h = (_Float16*)(wsb + 65536);            // 256 B
    int*      cnt = (int*)(wsb + 65792);                 // 16 KiB (4096 ints)
    size_t off = 65792 + 16384;
    _Float16* us = (_Float16*)(wsb + off);  off += (size_t)Ms * 256;  // f16
    _Float16* uc = (_Float16*)(wsb + off);  off += (size_t)Mc * 256;
    unsigned* rcB = (unsigned*)(wsb + off); off += (size_t)NB * NR * CAPS * 4;
    int*   pos  = (int*)(wsb + off);   off += (size_t)E * 4;
    float* outB = (float*)(wsb + off); off += (size_t)NB * NR * CAPS * 4;
    const bool bucketed = (off <= ws_size);

    const int nbs = (Ms + 63) / 64, nbc = (Mc + 63) / 64;

    conv_w<<<9, 256, 0, stream>>>(W1, W2, Wt, w2h, cnt);
    gemm_u<<<nbs + nbc, 256, 0, stream>>>(zs, zc, Wt, b1, us, uc, Ms, Mc, nbs);
    if (bucketed) {
        bucket_scatter<<<(E + 1023) / 1024, 256, 0, stream>>>(
            row, col, rcB, pos, cnt, E, (float)NB / (float)Ms);
        edge_bucket<<<2048, 256, 0, stream>>>(rcB, cnt, us, uc, w2h, b2, outB);
        unscatter<<<(E + 1023) / 1024, 256, 0, stream>>>(
            pos, outB, row, col, us, uc, w2h, b2, out, E);
    } else {
        edge_kernel<<<(E + 31) / 32, 256, 0, stream>>>(row, col, us, uc, w2h, b2, out, E);
    }
    (void)n_in; (void)out_size;
}